// Round 1
// 243.382 us; speedup vs baseline: 1.0101x; 1.0101x over previous
//
#include <hip/hip_runtime.h>

// QuadraticBaseMorpho: out[h][w] = max_{dy,dx in [-3,3]} xpad[h+dy][w+dx] + nb[dy+3][dx+3]
// xpad = x padded with -10000. nb = -(se/se.max()) with center forced to -10000.
// se = k1*xg^2 + 2*k2*xg*yg + k3*yg^2 is even-symmetric -> the [::-1,::-1] flip is identity.
// Input (8,64,256,256) fp32 = 512 planes of 256x256.
//
// Structure: 2048 blocks; each block = 64 rows of one plane, processed as 4
// sub-tiles of 16 rows over a 22-row LDS ring (ring == vertical window; staged
// rows for s+1 overwrite only rows dead after sub-tile s's barrier; the 6
// carried halo rows 16s+16..21 live at disjoint slots). 23232 B -> 7 blocks/CU.
//
// Inner loop: packed-fp32 rewrite. The 49 adds/output pack into v_pk_add_f32
// pairs (s0,s1)(s2,s3)(s4,s5)+s6. Odd output columns take even-aligned vf2
// sub-pairs straight from the ds_read_b128 quads (zero copies); even columns
// need odd-start pairs, materialized once per row with 4 two-mov shuffles and
// shared across all 4 t's. Weight pairs (w0,w1)(w2,w3)(w4,w5)+w6 = 49 SGPRs,
// same footprint as the scalar w[49]. Per (t,c): 3 pk_add + 1 add + 3 max3 +
// 1 max = 8 issues vs 11 scalar (-19% VALU issue incl. mov overhead).

#define MAXV 10000.0f

constexpr int H = 256;
constexpr int W = 256;
constexpr int SUB = 16;              // output rows per sub-tile
constexpr int NSUB = 4;              // sub-tiles per block (64 rows)
constexpr int RING = 22;             // LDS ring rows == vertical window (16+6)
constexpr int LSTR = 264;            // floats/row: 4 left halo + 256 + 4 right
constexpr int R = 4;                 // output rows per thread

typedef float vf4 __attribute__((ext_vector_type(4)));
typedef float vf2 __attribute__((ext_vector_type(2)));

__global__ __launch_bounds__(256, 6) void morpho_kernel(
    const float* __restrict__ x,
    const float* __restrict__ k1p,
    const float* __restrict__ k2p,
    const float* __restrict__ k3p,
    float* __restrict__ out) {
  __shared__ __align__(16) float tile[RING * LSTR];   // 23232 B -> 7 blocks/CU

  const int tid = threadIdx.x;
  const int lane = tid & 63;
  const int wid = __builtin_amdgcn_readfirstlane(tid >> 6);  // wave id, pinned uniform
  const int p = blockIdx.x >> 2;                 // plane (512)
  const int ty0 = (blockIdx.x & 3) * 64;         // block's first output row

  const float* __restrict__ xp = x + (size_t)p * (H * W);
  float* __restrict__ op = out + (size_t)p * (H * W);

  // ---- halo cols 0..3 / 260..263: set once for all ring rows (never rewritten) ----
  if (tid < RING * 8) {
    const int h = tid & 7;
    const int col = (h < 4) ? h : (256 + h);
    tile[(tid >> 3) * LSTR + col] = -MAXV;
  }

  // ---- prologue: stage local rows 0..21 (gy = ty0-3+r); slot == local row ----
  for (int i = tid; i < 22 * 64; i += 256) {
    const int r = i >> 6;
    const int c = i & 63;
    const int gy = ty0 - 3 + r;                  // <= 210, only gy<0 needs clamp
    vf4 v;
    if (gy >= 0) {
      v = *reinterpret_cast<const vf4*>(&xp[gy * W + c * 4]);
    } else {
      v.x = v.y = v.z = v.w = -MAXV;
    }
    *reinterpret_cast<vf4*>(&tile[r * LSTR + 4 + c * 4]) = v;
  }

  // ---- SE: one weight per lane (8x8 grid), shuffle-max, readlane -> SGPRs ----
  const float k1v = k1p[0], k2v = k2p[0], k3v = k3p[0];
  const int ia = lane >> 3, ib = lane & 7;
  const float xg = (float)(((ib < 6) ? ib : 6) - 3);   // clamp dup lanes; max unaffected
  const float yg = (float)(((ia < 6) ? ia : 6) - 3);
  const float sev = k1v * (xg * xg) + 2.0f * k2v * (xg * yg) + k3v * (yg * yg);
  float mx = sev;
#pragma unroll
  for (int off = 32; off; off >>= 1) mx = fmaxf(mx, __shfl_xor(mx, off, 64));
  const float wv = 0.0f - sev * (1.0f / mx);

  // weight row d: pairs (w0,w1)(w2,w3)(w4,w5) + scalar w6 -> 49 SGPRs total
  vf2 wp[7][3];
  float w6[7];
#pragma unroll
  for (int d = 0; d < 7; ++d) {
#pragma unroll
    for (int m = 0; m < 3; ++m) {
      vf2 pr;
      pr.x = __int_as_float(__builtin_amdgcn_readlane(__float_as_int(wv), d * 8 + 2 * m));
      pr.y = __int_as_float(__builtin_amdgcn_readlane(__float_as_int(wv), d * 8 + 2 * m + 1));
      wp[d][m] = pr;
    }
    w6[d] = __int_as_float(__builtin_amdgcn_readlane(__float_as_int(wv), d * 8 + 6));
  }
  wp[3][1].y = -MAXV;                            // masked center (d=3, j=3)

  __syncthreads();

  // ---- sub-tile loop: compute s while next 16 rows' loads are in flight ----
#pragma unroll
  for (int s = 0; s < NSUB; ++s) {
    // issue staging loads (wave wid -> new rows wid*4..wid*4+3, lane -> chunk)
    vf4 stg[4];
    if (s < NSUB - 1) {
#pragma unroll
      for (int j = 0; j < 4; ++j) {
        const int gy = ty0 + 19 + 16 * s + wid * 4 + j;  // wave-uniform row
        if (gy < H) {
          stg[j] = *reinterpret_cast<const vf4*>(&xp[gy * W + lane * 4]);
        } else {
          stg[j].x = stg[j].y = stg[j].z = stg[j].w = -MAXV;
        }
      }
    }

    // compute sub-tile s: window = local rows 16s .. 16s+21 (mod 22)
    int sb0 = (16 * s) % RING + wid * 4;         // compile-time % ; <= 28
    if (sb0 >= RING) sb0 -= RING;
    const float* baseA = &tile[sb0 * LSTR + lane * 4];
    const float* baseB = baseA - RING * LSTR;
    const int thresh = RING - sb0;               // iy >= thresh wraps (uniform)

    float acc[R][4];
#pragma unroll
    for (int t = 0; t < R; ++t)
#pragma unroll
      for (int c = 0; c < 4; ++c) acc[t][c] = -INFINITY;

#pragma unroll
    for (int iy = 0; iy < R + 6; ++iy) {         // local rows sb0+iy (ring)
      const float* rp = ((iy >= thresh) ? baseB : baseA) + iy * LSTR;
      const vf4 q0 = *reinterpret_cast<const vf4*>(rp);      // buf[0..3]
      const vf4 q1 = *reinterpret_cast<const vf4*>(rp + 4);  // buf[4..7]
      const vf4 q2 = *reinterpret_cast<const vf4*>(rp + 8);  // buf[8..11]

      // odd-start pairs (copies, shared across t): (b1,b2)(b3,b4)(b5,b6)(b7,b8)
      const vf2 O0 = __builtin_shufflevector(q0, q0, 1, 2);
      const vf2 O1 = __builtin_shufflevector(q0, q1, 3, 4);
      const vf2 O2 = __builtin_shufflevector(q1, q1, 1, 2);
      const vf2 O3 = __builtin_shufflevector(q1, q2, 3, 4);
      // even-start pairs (free quad sub-pairs): (b2,b3)(b4,b5)(b6,b7)(b8,b9)
      const vf2 E0 = __builtin_shufflevector(q0, q0, 2, 3);
      const vf2 E1 = __builtin_shufflevector(q1, q1, 0, 1);
      const vf2 E2 = __builtin_shufflevector(q1, q1, 2, 3);
      const vf2 E3 = __builtin_shufflevector(q2, q2, 0, 1);

      // per output col c: pairs (s0,s1)(s2,s3)(s4,s5), tail scalar s6 = buf[c+7]
      const vf2 P[4][3] = {{O0, O1, O2}, {E0, E1, E2}, {O1, O2, O3}, {E1, E2, E3}};
      const float T[4] = {q1.w, q2.x, q2.y, q2.z};

#pragma unroll
      for (int t = 0; t < R; ++t) {
        const int dyr = iy - t;                  // nb row index = dy+3
        if (dyr < 0 || dyr > 6) continue;        // dead after unroll
#pragma unroll
        for (int c = 0; c < 4; ++c) {
          const vf2 a = P[c][0] + wp[dyr][0];    // v_pk_add_f32
          const vf2 b = P[c][1] + wp[dyr][1];    // v_pk_add_f32
          const vf2 g = P[c][2] + wp[dyr][2];    // v_pk_add_f32
          const float s6 = T[c] + w6[dyr];
          const float m0 = fmaxf(fmaxf(a.x, a.y), b.x);   // v_max3
          const float m1 = fmaxf(fmaxf(b.y, g.x), g.y);   // v_max3
          const float m2 = fmaxf(fmaxf(s6, m0), m1);      // v_max3
          acc[t][c] = fmaxf(acc[t][c], m2);
        }
      }
    }

    // store sub-tile s (plain float4; lane-contiguous 1024 B per wave)
#pragma unroll
    for (int t = 0; t < R; ++t) {
      const int gy = ty0 + 16 * s + wid * 4 + t;
      vf4 v;
      v.x = acc[t][0];
      v.y = acc[t][1];
      v.z = acc[t][2];
      v.w = acc[t][3];
      *reinterpret_cast<vf4*>(&op[gy * W + lane * 4]) = v;
    }

    // commit staged rows into ring slots (old contents dead after barrier)
    __syncthreads();                             // all waves done reading window s
    if (s < NSUB - 1) {
#pragma unroll
      for (int j = 0; j < 4; ++j) {
        int sb = (16 * s) % RING + wid * 4 + j;  // == (22+16s+wid*4+j) % 22
        if (sb >= RING) sb -= RING;
        *reinterpret_cast<vf4*>(&tile[sb * LSTR + 4 + lane * 4]) = stg[j];
      }
      __syncthreads();                           // new rows visible for s+1
    }
  }
}

extern "C" void kernel_launch(void* const* d_in, const int* in_sizes, int n_in,
                              void* d_out, int out_size, void* d_ws, size_t ws_size,
                              hipStream_t stream) {
  const float* x = (const float*)d_in[0];
  const float* k1 = (const float*)d_in[1];
  const float* k2 = (const float*)d_in[2];
  const float* k3 = (const float*)d_in[3];
  float* outp = (float*)d_out;

  const int planes = 8 * 64;                     // 512
  const int blocks = planes * 4;                 // 2048 (64 rows per block)
  morpho_kernel<<<dim3(blocks), dim3(256), 0, stream>>>(x, k1, k2, k3, outp);
}